// Round 1
// baseline (1345.364 us; speedup 1.0000x reference)
//
#include <hip/hip_runtime.h>
#include <math.h>

// NPCLoss: B=8192 rows, C=32000 cols fp32 logits + int32 targets -> scalar f32.
// Phase 1: per-row fused top2 + target-logit + logsumexp -> loss[row], negflag[row].
// Phase 2: single block: sort losses, cumsum, threshold mask, final scalar.

// ---------------- Kernel 1: per-row reduction ----------------

__device__ inline void upd(float v, float& m1, float& m2, float& s) {
    float nm1 = fmaxf(m1, v);
    m2 = fmaxf(fminf(m1, v), m2);       // second-largest update (branch-free)
    s  = s * __expf(m1 - nm1) + __expf(v - nm1);
    m1 = nm1;
}

__global__ __launch_bounds__(256) void npc_row_kernel(
        const float* __restrict__ logits,
        const int* __restrict__ target,
        float* __restrict__ loss,
        int* __restrict__ negflag,
        int C) {
    const int row = blockIdx.x;
    const int tid = threadIdx.x;
    const float* rp = logits + (size_t)row * (size_t)C;

    float tg = 0.0f;
    if (tid == 0) tg = rp[target[row]];

    float m1 = -INFINITY, m2 = -INFINITY, s = 0.0f;

    const int C4 = C >> 2;
    const float4* rp4 = (const float4*)rp;
    for (int c = tid; c < C4; c += 256) {
        float4 v = rp4[c];
        upd(v.x, m1, m2, s);
        upd(v.y, m1, m2, s);
        upd(v.z, m1, m2, s);
        upd(v.w, m1, m2, s);
    }
    // tail (C % 4) — C=32000 is divisible by 4, kept for safety
    for (int c = (C4 << 2) + tid; c < C; c += 256) {
        upd(rp[c], m1, m2, s);
    }

    // wave (64-lane) butterfly reduce of (m1, m2, s)
    for (int off = 32; off; off >>= 1) {
        float om1 = __shfl_xor(m1, off);
        float om2 = __shfl_xor(m2, off);
        float os  = __shfl_xor(s,  off);
        float nm1 = fmaxf(m1, om1);
        m2 = fmaxf(fminf(m1, om1), fmaxf(m2, om2));
        s  = s * __expf(m1 - nm1) + os * __expf(om1 - nm1);
        m1 = nm1;
    }

    __shared__ float sm1[4], sm2[4], ss[4];
    const int w = tid >> 6;
    if ((tid & 63) == 0) { sm1[w] = m1; sm2[w] = m2; ss[w] = s; }
    __syncthreads();

    if (tid == 0) {
        float rm1 = sm1[0], rm2 = sm2[0], rs = ss[0];
        #pragma unroll
        for (int i = 1; i < 4; i++) {
            float om1 = sm1[i], om2 = sm2[i], os = ss[i];
            float nm1 = fmaxf(rm1, om1);
            rm2 = fmaxf(fminf(rm1, om1), fmaxf(rm2, om2));
            rs  = rs * __expf(rm1 - nm1) + os * __expf(om1 - nm1);
            rm1 = nm1;
        }
        float lse = rm1 + __logf(rs);
        float margin1 = tg - rm1;
        float margin  = (margin1 != 0.0f) ? margin1 : (tg - rm2);
        float lv = (margin >= 0.0f) ? fmaxf(0.0f, 1.0f - margin)
                                    : fmaxf(0.0f, 1.0f - tg + lse);
        loss[row]    = lv;
        negflag[row] = (margin < 0.0f) ? 1 : 0;
    }
}

// ---------------- Kernel 2: sort + cumsum + threshold ----------------
// Single block, 1024 threads. P = pow2 >= B (here P == B == 8192, E = 8).

__global__ __launch_bounds__(1024) void npc_final_kernel(
        const float* __restrict__ loss,
        const int* __restrict__ negflag,
        float* __restrict__ outv,
        int B, int P) {
    extern __shared__ float sl[];           // P floats
    const int tid  = threadIdx.x;
    const int nthr = blockDim.x;            // 1024
    const int w = tid >> 6, l = tid & 63;

    __shared__ int    wneg[16];
    __shared__ double wtot[16];
    __shared__ int    wcnt[16];
    __shared__ double ws1[16];

    // load losses into LDS + count negatives
    int myneg = 0;
    for (int i = tid; i < P; i += nthr) {
        if (i < B) { sl[i] = loss[i]; myneg += negflag[i]; }
        else       { sl[i] = INFINITY; }
    }
    for (int off = 32; off; off >>= 1) myneg += __shfl_down(myneg, off);
    if (l == 0) wneg[w] = myneg;
    __syncthreads();

    // bitonic sort ascending
    for (int k = 2; k <= P; k <<= 1) {
        for (int j = k >> 1; j > 0; j >>= 1) {
            for (int p = tid; p < (P >> 1); p += nthr) {
                int i   = ((p & ~(j - 1)) << 1) | (p & (j - 1));
                int ixj = i | j;
                bool up = ((i & k) == 0);
                float a = sl[i], b = sl[ixj];
                if ((a > b) == up) { sl[i] = b; sl[ixj] = a; }
            }
            __syncthreads();
        }
    }

    // hierarchical inclusive prefix sum in double; each thread owns 8 elems
    const int E = P / nthr;                  // == 8
    const int base = tid * E;
    double lcum[8];
    double run = 0.0;
    #pragma unroll
    for (int r = 0; r < 8; r++) {
        run += (double)sl[base + r];
        lcum[r] = run;
    }
    const double tot = run;
    double sc = tot;                         // inclusive scan of thread totals
    for (int off = 1; off < 64; off <<= 1) {
        double o = __shfl_up(sc, off);
        if (l >= off) sc += o;
    }
    if (l == 63) wtot[w] = sc;
    __syncthreads();
    double woff = 0.0;
    for (int i = 0; i < w; i++) woff += wtot[i];
    const double excl = woff + sc - tot;     // exclusive offset for this thread

    // neg count total (wneg written before sort barriers, still valid)
    int negc = 0;
    #pragma unroll
    for (int i = 0; i < 16; i++) negc += wneg[i];

    const double thrD = 0.81 * (double)B + 0.9 * (double)negc;
    const float  thrF = (float)thrD;

    // mask test in fp32 to mirror reference rounding
    int cnt = 0; double s1 = 0.0;
    #pragma unroll
    for (int r = 0; r < 8; r++) {
        int i = base + r;
        if (i < B) {
            float cumf = (float)(excl + lcum[r]);
            float rhs  = thrF + 1.0f - (float)i;
            if (cumf <= rhs) { cnt++; s1 += (double)sl[i]; }
        }
    }
    for (int off = 32; off; off >>= 1) {
        cnt += __shfl_down(cnt, off);
        s1  += __shfl_down(s1,  off);
    }
    if (l == 0) { wcnt[w] = cnt; ws1[w] = s1; }
    __syncthreads();

    if (tid == 0) {
        int cc = 0; double SS = 0.0;
        #pragma unroll
        for (int i = 0; i < 16; i++) { cc += wcnt[i]; SS += ws1[i]; }
        float npcl1 = (float)SS;
        float countf = (float)cc;
        float npcl2 = thrF - countf;
        outv[0] = fmaxf(npcl1, npcl2) / countf;
    }
}

// ---------------- host launch ----------------

extern "C" void kernel_launch(void* const* d_in, const int* in_sizes, int n_in,
                              void* d_out, int out_size, void* d_ws, size_t ws_size,
                              hipStream_t stream) {
    const float* logits = (const float*)d_in[0];
    const int*   target = (const int*)d_in[1];
    float* outv = (float*)d_out;

    const int B = in_sizes[1];
    const int C = in_sizes[0] / B;

    float* loss    = (float*)d_ws;
    int*   negflag = (int*)((char*)d_ws + (size_t)B * sizeof(float));

    int P = 1;
    while (P < B) P <<= 1;

    hipLaunchKernelGGL(npc_row_kernel, dim3(B), dim3(256), 0, stream,
                       logits, target, loss, negflag, C);
    hipLaunchKernelGGL(npc_final_kernel, dim3(1), dim3(1024),
                       (size_t)P * sizeof(float), stream,
                       loss, negflag, outv, B, P);
}